// Round 8
// baseline (241.422 us; speedup 1.0000x reference)
//
#include <hip/hip_runtime.h>
#include <math.h>

#define T_TOKENS 16384
#define D_DIM    2048
#define E_EXP    64
#define TOPK     8
#define NS       8              // split-K slices
#define NCH      (D_DIM / NS / 32)   // 8 k-chunks of 32 per slice

typedef __attribute__((ext_vector_type(8))) short bf16x8;
typedef __attribute__((ext_vector_type(4))) float f32x4;

__device__ __forceinline__ unsigned short bf16rne(float f) {
  unsigned u = __builtin_bit_cast(unsigned, f);
  unsigned r = u + 0x7fffu + ((u >> 16) & 1u);
  return (unsigned short)(r >> 16);
}
__device__ __forceinline__ float bf16f(unsigned short h) {
  return __builtin_bit_cast(float, (unsigned)h << 16);
}

// Split 8 floats into hi/lo bf16x8 fragments (x = hi + lo, |lo| <~ 2^-9 |x|).
__device__ __forceinline__ void split8(const float4 v0, const float4 v1,
                                       bf16x8& hi, bf16x8& lo) {
  const float xs[8] = {v0.x, v0.y, v0.z, v0.w, v1.x, v1.y, v1.z, v1.w};
  #pragma unroll
  for (int j = 0; j < 8; ++j) {
    unsigned short h = bf16rne(xs[j]);
    hi[j] = (short)h;
    lo[j] = (short)bf16rne(xs[j] - bf16f(h));
  }
}

// ---------------- Kernel 0: pre-convert gate_w to frag-ordered bf16 hi/lo ----
// entry id = ((c*4 + kq)*64 + e): c = k/32 chunk, kq = k-quad, e = expert.
// Entry = 8 bf16 (16 B) = g[e][c*32 + kq*8 .. +7]. Also zeroes counts region.
__global__ __launch_bounds__(256) void convert_g_kernel(
    const float* __restrict__ gw, unsigned short* __restrict__ ph,
    unsigned short* __restrict__ pl, float* __restrict__ counts_zero)
{
  const int id = blockIdx.x * 256 + threadIdx.x;   // 0..16383
  if (blockIdx.x == 0 && threadIdx.x < E_EXP) counts_zero[threadIdx.x] = 0.0f;

  const int e  = id & 63;
  const int kq = (id >> 6) & 3;
  const int c  = id >> 8;
  const float* gp = &gw[(size_t)e * D_DIM + c * 32 + kq * 8];
  float4 v0 = *(const float4*)&gp[0];
  float4 v1 = *(const float4*)&gp[4];
  bf16x8 hi, lo;
  split8(v0, v1, hi, lo);
  *(bf16x8*)&ph[(size_t)id * 8] = hi;
  *(bf16x8*)&pl[(size_t)id * 8] = lo;
}

// ---------------- Kernel 1: partial logits via split-bf16 MFMA ----------------
// grid (T/64, NS), 256 thr = 4 waves, no LDS/barriers.
// WAVE TILE 16 tok x 64 exp (halved vs R7): live VGPRs ~65 (acc 16, A 8,
// x 8, transient B 8, addr ~12) -- far under the 128 cap of
// __launch_bounds__(256,4), so no scratch spill and the scheduler has
// headroom to pipeline loads itself (R6/R7 at ~110-130 live were stuck at
// 76 us = spill-bound theory). 3 MFMA terms: ah*bh + al*bh + ah*bl.
__global__ __launch_bounds__(256, 4) void moe_logits_kernel(
    const float* __restrict__ x, const unsigned short* __restrict__ ph,
    const unsigned short* __restrict__ pl, float* __restrict__ part)
{
  const int tid  = threadIdx.x;
  const int wave = tid >> 6;
  const int lane = tid & 63;
  const int l15  = lane & 15;
  const int quad = lane >> 4;
  const int ks   = blockIdx.y;
  const int k0   = ks * (D_DIM / NS);
  const int tokw = blockIdx.x * 64 + wave * 16;   // wave's 16 tokens

  f32x4 acc[4];
  #pragma unroll
  for (int et = 0; et < 4; ++et) acc[et] = (f32x4){0.f, 0.f, 0.f, 0.f};

  // x pointer: A[m=l15][k=quad*8+j]; advance 128 B (32 floats) per chunk.
  const float* xp = &x[(size_t)(tokw + l15) * D_DIM + k0 + quad * 8];
  // B pointers: entry ((cg*4+quad)*64 + l15)*8 shorts; et offset = 256 B imm.
  const unsigned short* bh_p = &ph[(((size_t)(k0 >> 5) * 4 + quad) * 64 + l15) * 8];
  const unsigned short* bl_p = &pl[(((size_t)(k0 >> 5) * 4 + quad) * 64 + l15) * 8];

  #pragma unroll 2
  for (int c = 0; c < NCH; ++c) {
    float4 v0 = *(const float4*)&xp[0];
    float4 v1 = *(const float4*)&xp[4];
    xp += 32;

    bf16x8 ah, al;
    split8(v0, v1, ah, al);

    #pragma unroll
    for (int et = 0; et < 4; ++et) {
      bf16x8 bh = *(const bf16x8*)&bh_p[et * 128];
      bf16x8 bl = *(const bf16x8*)&bl_p[et * 128];
      acc[et] = __builtin_amdgcn_mfma_f32_16x16x32_bf16(ah, bh, acc[et], 0, 0, 0);
      acc[et] = __builtin_amdgcn_mfma_f32_16x16x32_bf16(al, bh, acc[et], 0, 0, 0);
      acc[et] = __builtin_amdgcn_mfma_f32_16x16x32_bf16(ah, bl, acc[et], 0, 0, 0);
    }
    bh_p += 2048;   // next 32-k chunk: 4 KB = 2048 shorts
    bl_p += 2048;
  }

  // ---- store partials: D row(m) = quad*4 + r (token), col(n) = l15 (expert) ----
  #pragma unroll
  for (int et = 0; et < 4; ++et) {
    #pragma unroll
    for (int r = 0; r < 4; ++r) {
      const size_t t = (size_t)tokw + quad * 4 + r;
      part[((size_t)ks * T_TOKENS + t) * E_EXP + et * 16 + l15] = acc[et][r];
    }
  }
}

// ---------------- Kernel 2: reduce + bias, top-8, softmax, counts ----------------
__global__ __launch_bounds__(64) void topk_kernel(
    const float* __restrict__ part, const float* __restrict__ bias,
    float* __restrict__ out)
{
  __shared__ unsigned hist[E_EXP];
  const int tid = threadIdx.x;            // 0..63
  const int t = blockIdx.x * 64 + tid;
  hist[tid] = 0;
  __syncthreads();

  float l[E_EXP];
  #pragma unroll
  for (int j = 0; j < E_EXP / 4; ++j) {
    float4 b = *(const float4*)&bias[j * 4];
    l[4*j] = b.x; l[4*j+1] = b.y; l[4*j+2] = b.z; l[4*j+3] = b.w;
  }
  #pragma unroll 1
  for (int ks = 0; ks < NS; ++ks) {
    const float4* p = (const float4*)&part[((size_t)ks * T_TOKENS + t) * E_EXP];
    #pragma unroll
    for (int j = 0; j < E_EXP / 4; ++j) {
      float4 v = p[j];
      l[4*j] += v.x; l[4*j+1] += v.y; l[4*j+2] += v.z; l[4*j+3] += v.w;
    }
  }

  float tv[TOPK]; int tix[TOPK];
  unsigned long long used = 0ull;
  #pragma unroll
  for (int k = 0; k < TOPK; ++k) {
    float best = -INFINITY; int bi = 0;
    #pragma unroll
    for (int j = 0; j < E_EXP; ++j) {
      bool ok = (((used >> j) & 1ull) == 0ull) && (l[j] > best);  // strict >: lowest index wins ties
      best = ok ? l[j] : best;
      bi   = ok ? j : bi;
    }
    tv[k] = best; tix[k] = bi;
    used |= (1ull << bi);
  }

  float m = tv[0], s = 0.0f, w[TOPK];
  #pragma unroll
  for (int k = 0; k < TOPK; ++k) { w[k] = expf(tv[k] - m); s += w[k]; }
  float inv = 1.0f / s;

  #pragma unroll
  for (int k = 0; k < TOPK; ++k) {
    out[(size_t)t * TOPK + k] = (float)tix[k];                        // indices as fp32
    out[(size_t)T_TOKENS * TOPK + (size_t)t * TOPK + k] = w[k] * inv; // weights
  }

  #pragma unroll
  for (int k = 0; k < TOPK; ++k) atomicAdd(&hist[tix[k]], 1u);
  __syncthreads();
  atomicAdd(&out[2 * (size_t)T_TOKENS * TOPK + tid], (float)hist[tid]);
}

extern "C" void kernel_launch(void* const* d_in, const int* in_sizes, int n_in,
                              void* d_out, int out_size, void* d_ws, size_t ws_size,
                              hipStream_t stream) {
  const float* x    = (const float*)d_in[0];
  const float* gw   = (const float*)d_in[1];
  const float* bias = (const float*)d_in[2];
  float* out  = (float*)d_out;

  // ws layout: part (NS*4 MB) | ph (256 KB) | pl (256 KB)
  float* part = (float*)d_ws;
  const size_t part_elems = (size_t)NS * T_TOKENS * E_EXP;
  unsigned short* ph = (unsigned short*)((char*)d_ws + part_elems * sizeof(float));
  unsigned short* pl = ph + (size_t)E_EXP * D_DIM;

  convert_g_kernel<<<dim3(E_EXP * D_DIM / 8 / 256), dim3(256), 0, stream>>>(
      gw, ph, pl, out + 2 * (size_t)T_TOKENS * TOPK);
  moe_logits_kernel<<<dim3(T_TOKENS / 64, NS), dim3(256), 0, stream>>>(
      x, ph, pl, part);
  topk_kernel<<<dim3(T_TOKENS / 64), dim3(64), 0, stream>>>(part, bias, out);
}

// Round 9
// 230.631 us; speedup vs baseline: 1.0468x; 1.0468x over previous
//
#include <hip/hip_runtime.h>
#include <math.h>

#define T_TOKENS 16384
#define D_DIM    2048
#define E_EXP    64
#define TOPK     8
#define NS       4                   // split-K slices
#define KC       32                  // k per chunk
#define NCH      (D_DIM / NS / KC)   // 16 chunks per slice
#define TT       64                  // tokens per block
#define XS       65                  // xl[k][t] row stride: reads conflict-free, writes <=2-way

typedef __attribute__((ext_vector_type(8))) short bf16x8;
typedef __attribute__((ext_vector_type(4))) float f32x4;

__device__ __forceinline__ unsigned short bf16rne(float f) {
  unsigned u = __builtin_bit_cast(unsigned, f);
  unsigned r = u + 0x7fffu + ((u >> 16) & 1u);
  return (unsigned short)(r >> 16);
}
__device__ __forceinline__ float bf16f(unsigned short h) {
  return __builtin_bit_cast(float, (unsigned)h << 16);
}

// ---------------- Kernel 0: pre-convert gate_w to frag-ordered bf16 hi/lo ----
// entry id = ((c*4 + kq)*64 + e): c = k/32 chunk, kq = k-quad, e = expert.
// Entry = 8 bf16 (16 B) = g[e][c*32 + kq*8 .. +7]. Also zeroes counts region.
__global__ __launch_bounds__(256) void convert_g_kernel(
    const float* __restrict__ gw, unsigned short* __restrict__ ph,
    unsigned short* __restrict__ pl, float* __restrict__ counts_zero)
{
  const int id = blockIdx.x * 256 + threadIdx.x;   // 0..16383
  if (blockIdx.x == 0 && threadIdx.x < E_EXP) counts_zero[threadIdx.x] = 0.0f;

  const int e  = id & 63;
  const int kq = (id >> 6) & 3;
  const int c  = id >> 8;
  const float* gp = &gw[(size_t)e * D_DIM + c * 32 + kq * 8];
  float4 v0 = *(const float4*)&gp[0];
  float4 v1 = *(const float4*)&gp[4];
  const float xs[8] = {v0.x, v0.y, v0.z, v0.w, v1.x, v1.y, v1.z, v1.w};
  bf16x8 hi, lo;
  #pragma unroll
  for (int j = 0; j < 8; ++j) {
    unsigned short h = bf16rne(xs[j]);
    hi[j] = (short)h;
    lo[j] = (short)bf16rne(xs[j] - bf16f(h));
  }
  *(bf16x8*)&ph[(size_t)id * 8] = hi;
  *(bf16x8*)&pl[(size_t)id * 8] = lo;
}

// ---------------- Kernel 1: partial logits via split-bf16 MFMA ----------------
// grid (T/64, NS), 256 thr = 4 waves. Block tile 64 tok x 64 exp; wave w owns
// tokens [w*16, w*16+16). Canonical staged K-loop (m97 pattern):
//   - x chunk [64 tok][32 k] loaded COALESCED (8 lanes x 16 B per row) into
//     registers, written transposed to LDS xl[k][t] stride 65
//     (A-frag reads bank=(8q+j+16w+l15)%32: conflict-free; writes <=2-way)
//   - register prefetch of chunk c+1's x before computing chunk c
//   - all 8 B-frags (L2-hot packed bf16) loaded up-front -> one vmcnt, no
//     serial load chain (R8's failure: 32-VGPR schedule serialized B loads)
//   - 12 MFMA: (ah*bh + al*bh + ah*bl) x 4 expert tiles
__global__ __launch_bounds__(256, 4) void moe_logits_kernel(
    const float* __restrict__ x, const unsigned short* __restrict__ ph,
    const unsigned short* __restrict__ pl, float* __restrict__ part)
{
  __shared__ float xl[KC * XS];   // 8320 B

  const int tid  = threadIdx.x;
  const int wave = tid >> 6;
  const int lane = tid & 63;
  const int l15  = lane & 15;
  const int quad = lane >> 4;
  const int ks   = blockIdx.y;
  const int k0   = ks * (D_DIM / NS);
  const int tok0 = blockIdx.x * TT;
  const int tokw = tok0 + wave * 16;

  // staging map: thread -> rows (sr, sr+32), float4-col sc4 (coalesced 128B/row)
  const int sr  = tid >> 3;       // 0..31
  const int sc4 = tid & 7;        // 0..7

  f32x4 acc[4];
  #pragma unroll
  for (int et = 0; et < 4; ++et) acc[et] = (f32x4){0.f, 0.f, 0.f, 0.f};

  const unsigned short* bh_p = &ph[(((size_t)(k0 >> 5) * 4 + quad) * 64 + l15) * 8];
  const unsigned short* bl_p = &pl[(((size_t)(k0 >> 5) * 4 + quad) * 64 + l15) * 8];

  // ---- prologue: load chunk 0's x ----
  const float* xg0 = &x[(size_t)(tok0 + sr)      * D_DIM + k0 + sc4 * 4];
  const float* xg1 = &x[(size_t)(tok0 + sr + 32) * D_DIM + k0 + sc4 * 4];
  float4 p0 = *(const float4*)xg0;
  float4 p1 = *(const float4*)xg1;

  #pragma unroll 1
  for (int c = 0; c < NCH; ++c) {
    __syncthreads();              // previous chunk's compute done; LDS reusable
    // ---- transpose-write staged x to LDS: xl[k][t] ----
    {
      float* d0 = &xl[(sc4 * 4) * XS + sr];
      float* d1 = &xl[(sc4 * 4) * XS + sr + 32];
      d0[0*XS] = p0.x; d0[1*XS] = p0.y; d0[2*XS] = p0.z; d0[3*XS] = p0.w;
      d1[0*XS] = p1.x; d1[1*XS] = p1.y; d1[2*XS] = p1.z; d1[3*XS] = p1.w;
    }
    __syncthreads();

    // ---- prefetch next chunk's x (in flight during compute) ----
    if (c + 1 < NCH) {
      p0 = *(const float4*)(xg0 + (c + 1) * KC);
      p1 = *(const float4*)(xg1 + (c + 1) * KC);
    }

    // ---- all 8 B-frags for this chunk (L2-hot, 256 B segments) ----
    const unsigned short* ch = bh_p + (size_t)c * 2048;
    const unsigned short* cl = bl_p + (size_t)c * 2048;
    bf16x8 bh[4], bl[4];
    #pragma unroll
    for (int et = 0; et < 4; ++et) {
      bh[et] = *(const bf16x8*)&ch[et * 128];
      bl[et] = *(const bf16x8*)&cl[et * 128];
    }

    // ---- A-frag from LDS (conflict-free) + split to hi/lo bf16 ----
    float xr[8];
    #pragma unroll
    for (int j = 0; j < 8; ++j) xr[j] = xl[(quad * 8 + j) * XS + wave * 16 + l15];
    bf16x8 ah, al;
    #pragma unroll
    for (int j = 0; j < 8; ++j) {
      unsigned short h = bf16rne(xr[j]);
      ah[j] = (short)h;
      al[j] = (short)bf16rne(xr[j] - bf16f(h));
    }

    // ---- 12 MFMAs ----
    #pragma unroll
    for (int et = 0; et < 4; ++et) {
      acc[et] = __builtin_amdgcn_mfma_f32_16x16x32_bf16(ah, bh[et], acc[et], 0, 0, 0);
      acc[et] = __builtin_amdgcn_mfma_f32_16x16x32_bf16(al, bh[et], acc[et], 0, 0, 0);
      acc[et] = __builtin_amdgcn_mfma_f32_16x16x32_bf16(ah, bl[et], acc[et], 0, 0, 0);
    }
  }

  // ---- store partials: D row(m) = quad*4 + r (token), col(n) = l15 (expert) ----
  #pragma unroll
  for (int et = 0; et < 4; ++et) {
    #pragma unroll
    for (int r = 0; r < 4; ++r) {
      const size_t t = (size_t)tokw + quad * 4 + r;
      part[((size_t)ks * T_TOKENS + t) * E_EXP + et * 16 + l15] = acc[et][r];
    }
  }
}

// ---------------- Kernel 2: reduce + bias, top-8, softmax, counts ----------------
__global__ __launch_bounds__(64) void topk_kernel(
    const float* __restrict__ part, const float* __restrict__ bias,
    float* __restrict__ out)
{
  __shared__ unsigned hist[E_EXP];
  const int tid = threadIdx.x;            // 0..63
  const int t = blockIdx.x * 64 + tid;
  hist[tid] = 0;
  __syncthreads();

  float l[E_EXP];
  #pragma unroll
  for (int j = 0; j < E_EXP / 4; ++j) {
    float4 b = *(const float4*)&bias[j * 4];
    l[4*j] = b.x; l[4*j+1] = b.y; l[4*j+2] = b.z; l[4*j+3] = b.w;
  }
  #pragma unroll 1
  for (int ks = 0; ks < NS; ++ks) {
    const float4* p = (const float4*)&part[((size_t)ks * T_TOKENS + t) * E_EXP];
    #pragma unroll
    for (int j = 0; j < E_EXP / 4; ++j) {
      float4 v = p[j];
      l[4*j] += v.x; l[4*j+1] += v.y; l[4*j+2] += v.z; l[4*j+3] += v.w;
    }
  }

  float tv[TOPK]; int tix[TOPK];
  unsigned long long used = 0ull;
  #pragma unroll
  for (int k = 0; k < TOPK; ++k) {
    float best = -INFINITY; int bi = 0;
    #pragma unroll
    for (int j = 0; j < E_EXP; ++j) {
      bool ok = (((used >> j) & 1ull) == 0ull) && (l[j] > best);  // strict >: lowest index wins ties
      best = ok ? l[j] : best;
      bi   = ok ? j : bi;
    }
    tv[k] = best; tix[k] = bi;
    used |= (1ull << bi);
  }

  float m = tv[0], s = 0.0f, w[TOPK];
  #pragma unroll
  for (int k = 0; k < TOPK; ++k) { w[k] = expf(tv[k] - m); s += w[k]; }
  float inv = 1.0f / s;

  #pragma unroll
  for (int k = 0; k < TOPK; ++k) {
    out[(size_t)t * TOPK + k] = (float)tix[k];                        // indices as fp32
    out[(size_t)T_TOKENS * TOPK + (size_t)t * TOPK + k] = w[k] * inv; // weights
  }

  #pragma unroll
  for (int k = 0; k < TOPK; ++k) atomicAdd(&hist[tix[k]], 1u);
  __syncthreads();
  atomicAdd(&out[2 * (size_t)T_TOKENS * TOPK + tid], (float)hist[tid]);
}

extern "C" void kernel_launch(void* const* d_in, const int* in_sizes, int n_in,
                              void* d_out, int out_size, void* d_ws, size_t ws_size,
                              hipStream_t stream) {
  const float* x    = (const float*)d_in[0];
  const float* gw   = (const float*)d_in[1];
  const float* bias = (const float*)d_in[2];
  float* out  = (float*)d_out;

  // ws layout: part (NS*4 MB) | ph (256 KB) | pl (256 KB)
  float* part = (float*)d_ws;
  const size_t part_elems = (size_t)NS * T_TOKENS * E_EXP;
  unsigned short* ph = (unsigned short*)((char*)d_ws + part_elems * sizeof(float));
  unsigned short* pl = ph + (size_t)E_EXP * D_DIM;

  convert_g_kernel<<<dim3(E_EXP * D_DIM / 8 / 256), dim3(256), 0, stream>>>(
      gw, ph, pl, out + 2 * (size_t)T_TOKENS * TOPK);
  moe_logits_kernel<<<dim3(T_TOKENS / TT, NS), dim3(256), 0, stream>>>(
      x, ph, pl, part);
  topk_kernel<<<dim3(T_TOKENS / 64), dim3(64), 0, stream>>>(part, bias, out);
}